// Round 1
// baseline (492.325 us; speedup 1.0000x reference)
//
#include <hip/hip_runtime.h>

// Laplacian pyramid L1 loss, (32,3,512,512) fp32, 5 levels.
// Key identity: pyramids are linear, so compute pyramid of (input - target).
// Upsample(conv 4K of zero-stuffed) == direct polyphase filter on `down`:
//   even phase 1D taps (0.125, 0.75, 0.125), odd phase (0.5, 0.5).
// Reflection (np.pad 'reflect', no edge repeat) preserves parity, so the
// polyphase index map is exact at borders too.

#define BC 96  // 32 batch * 3 channels (depthwise => treat as independent planes)

__device__ __forceinline__ int refl(int i, int n) {
    // reflect without edge repeat; valid for i in [-(n-1), 2n-2]
    if (i < 0) i = -i;
    if (i >= n) i = 2 * n - 2 - i;
    return i;
}

// down[bc,y,x] = sum_{u,v} k1[u]k1[v] * src[refl(2y+u-2), refl(2x+v-2)]
// DIFF: src = inA - inB
template<bool DIFF>
__global__ void down_kernel(const float* __restrict__ inA,
                            const float* __restrict__ inB,
                            float* __restrict__ down, int H, int Hd) {
    int idx = blockIdx.x * blockDim.x + threadIdx.x;
    int total = BC * Hd * Hd;
    if (idx >= total) return;
    int x = idx % Hd;
    int t = idx / Hd;
    int y = t % Hd;
    int bc = t / Hd;

    const float k1[5] = {0.0625f, 0.25f, 0.375f, 0.25f, 0.0625f};
    size_t base = (size_t)bc * H * H;
    int rows[5], cols[5];
#pragma unroll
    for (int u = 0; u < 5; ++u) {
        rows[u] = refl(2 * y + u - 2, H);
        cols[u] = refl(2 * x + u - 2, H);
    }
    float acc = 0.f;
#pragma unroll
    for (int u = 0; u < 5; ++u) {
        const float* ra = inA + base + (size_t)rows[u] * H;
        float rs = 0.f;
        if (DIFF) {
            const float* rb = inB + base + (size_t)rows[u] * H;
#pragma unroll
            for (int v = 0; v < 5; ++v) rs += k1[v] * (ra[cols[v]] - rb[cols[v]]);
        } else {
#pragma unroll
            for (int v = 0; v < 5; ++v) rs += k1[v] * ra[cols[v]];
        }
        acc += k1[u] * rs;
    }
    down[idx] = acc;
}

// band: up = polyphase(down); local += |cur - up|; per-block partial to ws.
template<bool DIFF>
__global__ void band_kernel(const float* __restrict__ curA,
                            const float* __restrict__ curB,
                            const float* __restrict__ down,
                            int H, int Hd, float invN,
                            float* __restrict__ partial) {
    int total = BC * H * H;
    float local = 0.f;
    for (int idx = blockIdx.x * blockDim.x + threadIdx.x; idx < total;
         idx += gridDim.x * blockDim.x) {
        int x = idx % H;
        int t = idx / H;
        int y = t % H;
        int bc = t / H;
        const float* dp = down + (size_t)bc * Hd * Hd;

        int cx[3]; float wx[3];
        if ((x & 1) == 0) {
            cx[0] = refl(x - 2, H) >> 1; cx[1] = x >> 1; cx[2] = refl(x + 2, H) >> 1;
            wx[0] = 0.125f; wx[1] = 0.75f; wx[2] = 0.125f;
        } else {
            cx[0] = (x - 1) >> 1; cx[1] = refl(x + 1, H) >> 1; cx[2] = cx[0];
            wx[0] = 0.5f; wx[1] = 0.5f; wx[2] = 0.f;
        }
        int cy[3]; float wy[3];
        if ((y & 1) == 0) {
            cy[0] = refl(y - 2, H) >> 1; cy[1] = y >> 1; cy[2] = refl(y + 2, H) >> 1;
            wy[0] = 0.125f; wy[1] = 0.75f; wy[2] = 0.125f;
        } else {
            cy[0] = (y - 1) >> 1; cy[1] = refl(y + 1, H) >> 1; cy[2] = cy[0];
            wy[0] = 0.5f; wy[1] = 0.5f; wy[2] = 0.f;
        }
        float up = 0.f;
#pragma unroll
        for (int i = 0; i < 3; ++i) {
            const float* row = dp + (size_t)cy[i] * Hd;
            float rs = wx[0] * row[cx[0]] + wx[1] * row[cx[1]] + wx[2] * row[cx[2]];
            up += wy[i] * rs;
        }
        float cur = DIFF ? (curA[idx] - curB[idx]) : curA[idx];
        local += fabsf(cur - up);
    }
    // block reduction: wave64 shuffle, then LDS across 4 waves
#pragma unroll
    for (int off = 32; off > 0; off >>= 1)
        local += __shfl_down(local, off, 64);
    __shared__ float smem[4];
    int lane = threadIdx.x & 63;
    int wid = threadIdx.x >> 6;
    if (lane == 0) smem[wid] = local;
    __syncthreads();
    if (threadIdx.x == 0)
        partial[blockIdx.x] = (smem[0] + smem[1] + smem[2] + smem[3]) * invN;
}

__global__ void final_reduce(const float* __restrict__ partial, int n,
                             float* __restrict__ out) {
    float local = 0.f;
    for (int i = threadIdx.x; i < n; i += blockDim.x) local += partial[i];
#pragma unroll
    for (int off = 32; off > 0; off >>= 1)
        local += __shfl_down(local, off, 64);
    __shared__ float smem[4];
    int lane = threadIdx.x & 63;
    int wid = threadIdx.x >> 6;
    if (lane == 0) smem[wid] = local;
    __syncthreads();
    if (threadIdx.x == 0) out[0] = smem[0] + smem[1] + smem[2] + smem[3];
}

extern "C" void kernel_launch(void* const* d_in, const int* in_sizes, int n_in,
                              void* d_out, int out_size, void* d_ws, size_t ws_size,
                              hipStream_t stream) {
    const float* in = (const float*)d_in[0];
    const float* tg = (const float*)d_in[1];
    // d_in[2] is the Gaussian kernel (fixed binomial /256) -- hardcoded above.
    float* out = (float*)d_out;
    float* ws = (float*)d_ws;

    const int Hs[6] = {512, 256, 128, 64, 32, 16};
    float* down[5];
    size_t off = 0;
    for (int l = 0; l < 5; ++l) {
        down[l] = ws + off;
        off += (size_t)BC * Hs[l + 1] * Hs[l + 1];
    }
    const int PB = 2048;  // partial slots per level
    float* partial = ws + off;  // 5*PB floats
    hipMemsetAsync(partial, 0, 5 * PB * sizeof(float), stream);

    for (int l = 0; l < 5; ++l) {
        int H = Hs[l], Hd = Hs[l + 1];
        int nd = BC * Hd * Hd;
        int gd = (nd + 255) / 256;
        int nb = BC * H * H;
        int gb = (nb + 255) / 256;
        if (gb > PB) gb = PB;
        float invN = 1.f / (float)nb;
        if (l == 0) {
            down_kernel<true><<<gd, 256, 0, stream>>>(in, tg, down[0], H, Hd);
            band_kernel<true><<<gb, 256, 0, stream>>>(in, tg, down[0], H, Hd,
                                                      invN, partial + (size_t)l * PB);
        } else {
            down_kernel<false><<<gd, 256, 0, stream>>>(down[l - 1], nullptr, down[l], H, Hd);
            band_kernel<false><<<gb, 256, 0, stream>>>(down[l - 1], nullptr, down[l], H, Hd,
                                                       invN, partial + (size_t)l * PB);
        }
    }
    final_reduce<<<1, 256, 0, stream>>>(partial, 5 * PB, out);
}

// Round 2
// 353.287 us; speedup vs baseline: 1.3936x; 1.3936x over previous
//
#include <hip/hip_runtime.h>

// Laplacian pyramid L1 loss, (32,3,512,512) fp32, 5 levels, fused per level.
// Linearity: pyr_in[l] - pyr_tg[l] == pyramid(in - tg)[l], so one pyramid.
// Upsample(conv 4K of zero-stuffed) == polyphase on `down`:
//   even phase 1D taps (0.125, 0.75, 0.125), odd phase (0.5, 0.5).
// One kernel per level: stage 71x71 input tile -> LDS, compute 34x34 down
// tile (store 32x32 interior), compute 64x64 band |cur-up| from LDS only,
// block-reduce, atomicAdd scaled partial into out[0].

#define BC 96  // 32 batch * 3 channels (depthwise -> independent planes)

__device__ __forceinline__ int refl(int i, int n) {
    if (i < 0) i = -i;
    if (i >= n) i = 2 * n - 2 - i;
    return i;
}
// staging can overshoot past 2n-2 on the smallest level; reflect twice
__device__ __forceinline__ int refl2(int i, int n) {
    return refl(refl(i, n), n);
}

#define IN 71     // staged input tile (64 + 2*3 halo, covers down halo stencil)
#define IST 72    // padded stride
#define DN 34     // down tile incl. 1-halo
#define DST 36    // padded stride

template<bool DIFF>
__global__ __launch_bounds__(256) void lap_level(
        const float* __restrict__ A, const float* __restrict__ B,
        float* __restrict__ down, float* __restrict__ out,
        int H, int Hd, int T, float invN) {
    __shared__ float sIn[IN * IST];
    __shared__ float sDown[DN * DST];
    __shared__ float red[4];

    const int tid = threadIdx.x;
    const int tt = blockIdx.x % (T * T);
    const int bc = blockIdx.x / (T * T);
    const int ty = tt / T, tx = tt % T;
    const size_t ibase = (size_t)bc * H * H;
    const size_t dbase = (size_t)bc * Hd * Hd;
    const int r0 = 64 * ty - 4, c0 = 64 * tx - 4;
    const int dy0 = 32 * ty - 1, dx0 = 32 * tx - 1;

    // ---- stage input tile (diff at level 0) ----
    for (int i = tid; i < IN * IN; i += 256) {
        int r = i / IN, c = i - r * IN;
        int gr = refl2(r0 + r, H);
        int gc = refl2(c0 + c, H);
        size_t gidx = ibase + (size_t)gr * H + gc;
        float v = A[gidx];
        if (DIFF) v -= B[gidx];
        sIn[r * IST + c] = v;
    }
    __syncthreads();

    // ---- down tile: 5x5 binomial, stride 2 ----
    const float k1[5] = {0.0625f, 0.25f, 0.375f, 0.25f, 0.0625f};
    for (int i = tid; i < DN * DN; i += 256) {
        int dy = i / DN, dx = i - dy * DN;
        const float* p = &sIn[(2 * dy) * IST + 2 * dx];
        float acc = 0.f;
#pragma unroll
        for (int u = 0; u < 5; ++u) {
            const float* row = p + u * IST;
            acc += k1[u] * (k1[0] * row[0] + k1[1] * row[1] + k1[2] * row[2] +
                            k1[3] * row[3] + k1[4] * row[4]);
        }
        sDown[dy * DST + dx] = acc;
        int gdy = dy0 + dy, gdx = dx0 + dx;
        if ((unsigned)(dy - 1) < 32u && (unsigned)(dx - 1) < 32u &&
            gdy < Hd && gdx < Hd)
            down[dbase + (size_t)gdy * Hd + gdx] = acc;
    }
    __syncthreads();

    // ---- band: |cur - polyphase_up(down)|, all from LDS ----
    float local = 0.f;
    const int fy0 = 64 * ty, fx0 = 64 * tx;
    for (int i = tid; i < 64 * 64; i += 256) {
        int ly = i >> 6, lx = i & 63;
        int fy = fy0 + ly, fx = fx0 + lx;
        if (fy < H && fx < H) {
            float cur = sIn[(ly + 4) * IST + (lx + 4)];
            int ay0, ay1, ay2; float wy0, wy1, wy2;
            if ((fy & 1) == 0) {
                ay0 = (refl(fy - 2, H) >> 1) - dy0;
                ay1 = (fy >> 1) - dy0;
                ay2 = (refl(fy + 2, H) >> 1) - dy0;
                wy0 = 0.125f; wy1 = 0.75f; wy2 = 0.125f;
            } else {
                ay0 = ((fy - 1) >> 1) - dy0;
                ay1 = (refl(fy + 1, H) >> 1) - dy0;
                ay2 = ay0;
                wy0 = 0.5f; wy1 = 0.5f; wy2 = 0.f;
            }
            int ax0, ax1, ax2; float wx0, wx1, wx2;
            if ((fx & 1) == 0) {
                ax0 = (refl(fx - 2, H) >> 1) - dx0;
                ax1 = (fx >> 1) - dx0;
                ax2 = (refl(fx + 2, H) >> 1) - dx0;
                wx0 = 0.125f; wx1 = 0.75f; wx2 = 0.125f;
            } else {
                ax0 = ((fx - 1) >> 1) - dx0;
                ax1 = (refl(fx + 1, H) >> 1) - dx0;
                ax2 = ax0;
                wx0 = 0.5f; wx1 = 0.5f; wx2 = 0.f;
            }
            const float* r0p = &sDown[ay0 * DST];
            const float* r1p = &sDown[ay1 * DST];
            const float* r2p = &sDown[ay2 * DST];
            float up =
                wy0 * (wx0 * r0p[ax0] + wx1 * r0p[ax1] + wx2 * r0p[ax2]) +
                wy1 * (wx0 * r1p[ax0] + wx1 * r1p[ax1] + wx2 * r1p[ax2]) +
                wy2 * (wx0 * r2p[ax0] + wx1 * r2p[ax1] + wx2 * r2p[ax2]);
            local += fabsf(cur - up);
        }
    }

    // ---- block reduce + scaled atomic ----
#pragma unroll
    for (int off = 32; off > 0; off >>= 1)
        local += __shfl_down(local, off, 64);
    int lane = tid & 63, wid = tid >> 6;
    if (lane == 0) red[wid] = local;
    __syncthreads();
    if (tid == 0)
        atomicAdd(out, (red[0] + red[1] + red[2] + red[3]) * invN);
}

extern "C" void kernel_launch(void* const* d_in, const int* in_sizes, int n_in,
                              void* d_out, int out_size, void* d_ws, size_t ws_size,
                              hipStream_t stream) {
    const float* in = (const float*)d_in[0];
    const float* tg = (const float*)d_in[1];
    float* out = (float*)d_out;
    float* ws = (float*)d_ws;

    const int Hs[6] = {512, 256, 128, 64, 32, 16};
    float* down[5];
    size_t off = 0;
    for (int l = 0; l < 5; ++l) {
        down[l] = ws + off;
        off += (size_t)BC * Hs[l + 1] * Hs[l + 1];
    }

    hipMemsetAsync(out, 0, sizeof(float), stream);

    for (int l = 0; l < 5; ++l) {
        int H = Hs[l], Hd = Hs[l + 1];
        int T = (Hd + 31) / 32;
        int grid = BC * T * T;
        float invN = 1.f / ((float)BC * H * H);
        if (l == 0) {
            lap_level<true><<<grid, 256, 0, stream>>>(in, tg, down[0], out,
                                                      H, Hd, T, invN);
        } else {
            lap_level<false><<<grid, 256, 0, stream>>>(down[l - 1], nullptr,
                                                       down[l], out,
                                                       H, Hd, T, invN);
        }
    }
}